// Round 11
// baseline (391.029 us; speedup 1.0000x reference)
//
#include <hip/hip_runtime.h>

typedef unsigned int uint;
typedef unsigned short ushort;
typedef unsigned char uchar;
typedef __bf16 bf16x8 __attribute__((ext_vector_type(8)));
typedef float f32x4 __attribute__((ext_vector_type(4)));
typedef float f32x2 __attribute__((ext_vector_type(2)));

#define G1 256          // pass-1 blocks
#define SH 8            // 256 nodes per coarse bucket

__device__ __forceinline__ ushort f2b(float f) {
  union { float f; uint u; } x; x.f = f;
  uint r = x.u + 0x7fff + ((x.u >> 16) & 1);
  return (ushort)(r >> 16);
}
__device__ __forceinline__ float b2f(uint s) {
  union { uint u; float f; } x; x.u = s << 16;
  return x.f;
}

// unpack 2 bf16 packed in a uint -> float2
__device__ __forceinline__ f32x2 up2(uint u) {
  union { uint u; float f; } lo, hi;
  lo.u = u << 16;
  hi.u = u & 0xffff0000u;
  f32x2 r; r.x = lo.f; r.y = hi.f;
  return r;
}

__device__ __forceinline__ void gload_lds16(const void* g, void* l) {
  __builtin_amdgcn_global_load_lds(
      (const __attribute__((address_space(1))) void*)g,
      (__attribute__((address_space(3))) void*)l, 16, 0, 0);
}

// ---------------- pass 1a: histograms (x2 replicated) + folded weight prep ----------------
// Blocks [0,G1): histogram (512 thr). Blocks [G1,G1+72): weight prep (8 rids/block).
__global__ void p1hist(const int* __restrict__ src, const int* __restrict__ dst, int E,
                       int NBK, int SCN, int* __restrict__ H,
                       const float* __restrict__ W0, const float* __restrict__ W1,
                       const float* __restrict__ W2, const float* __restrict__ Wo,
                       ushort* __restrict__ Wt1, ushort* __restrict__ Wt2,
                       ushort* __restrict__ Wt3, ushort* __restrict__ Wz1,
                       ushort* __restrict__ Wz2, ushort* __restrict__ Wz3) {
  int t = threadIdx.x, b = blockIdx.x;
  if (b >= G1) {
    int rid = (b - G1) * 8 + (t >> 6);   // 0..575
    int tl = t & 63;
    if (rid < 384) {
      ushort* dstp; const float* W; int row;
      if (rid < 128)      { dstp = Wt1; W = W0; row = rid; }
      else if (rid < 256) { dstp = Wt2; W = W1; row = rid - 128; }
      else                { dstp = Wt3; W = W2; row = rid - 256; }
#pragma unroll
      for (int kk = 0; kk < 2; ++kk) {
        int k = tl + kk * 64;
        dstp[row * 128 + (k ^ ((row & 7) << 3))] = f2b(W[(size_t)k * 128 + row]);
      }
    } else if (rid < 512) {
      // Wz1/Wz2: [64][128] swizzled slabs of Wo (cols of Wo as rows)
      ushort* dstp = (rid < 448) ? Wz1 : Wz2;
      int row = (rid < 448) ? rid - 384 : rid - 448;
      int kbase = (rid < 448) ? 0 : 128;
#pragma unroll
      for (int kk = 0; kk < 2; ++kk) {
        int k = tl + kk * 64;
        dstp[row * 128 + (k ^ ((row & 7) << 3))] = f2b(Wo[(size_t)(kbase + k) * 64 + row]);
      }
    } else {
      // Wz3: [64][128] LINEAR (read directly as global B-fragments in agg_final)
      int row = rid - 512;
#pragma unroll
      for (int kk = 0; kk < 2; ++kk) {
        int k = tl + kk * 64;
        Wz3[row * 128 + k] = f2b(Wo[(size_t)(256 + k) * 64 + row]);
      }
    }
    return;
  }
  __shared__ int hd[2][512], hs[2][512];
  hd[0][t] = 0; hd[1][t] = 0; hs[0][t] = 0; hs[1][t] = 0;
  __syncthreads();
  int rep = t & 1;
  int chunk = (((E + G1 - 1) / G1) + 3) & ~3;
  int c0 = b * chunk, c1 = min(E, c0 + chunk);
  int e = c0 + t * 4;
  for (; e + 3 < c1; e += 2048) {
    int4 dv = *(const int4*)(dst + e);
    int4 sv = *(const int4*)(src + e);
    atomicAdd(&hd[rep][dv.x >> SH], 1); atomicAdd(&hd[rep][dv.y >> SH], 1);
    atomicAdd(&hd[rep][dv.z >> SH], 1); atomicAdd(&hd[rep][dv.w >> SH], 1);
    atomicAdd(&hs[rep][sv.x >> SH], 1); atomicAdd(&hs[rep][sv.y >> SH], 1);
    atomicAdd(&hs[rep][sv.z >> SH], 1); atomicAdd(&hs[rep][sv.w >> SH], 1);
  }
  for (; e < c1; ++e) {
    atomicAdd(&hd[rep][dst[e] >> SH], 1);
    atomicAdd(&hs[rep][src[e] >> SH], 1);
  }
  __syncthreads();
  for (int k = t; k < NBK; k += 512) {
    H[k * G1 + b] = hd[0][k] + hd[1][k];
    H[SCN + k * G1 + b] = hs[0][k] + hs[1][k];
  }
}

// ---------------- scan: per-block scan + blocksum ----------------
__global__ void scanA(const int* __restrict__ in, int n, int* __restrict__ out,
                      int* __restrict__ bsum) {
  __shared__ int sd[256];
  int t = threadIdx.x;
  int base = blockIdx.x * 2048 + t * 8;
  int v[8]; int s = 0;
#pragma unroll
  for (int k = 0; k < 8; ++k) { v[k] = (base + k < n) ? in[base + k] : 0; s += v[k]; }
  sd[t] = s;
  __syncthreads();
  for (int d = 1; d < 256; d <<= 1) {
    int tmp = (t >= d) ? sd[t - d] : 0;
    __syncthreads();
    if (t >= d) sd[t] += tmp;
    __syncthreads();
  }
  int run = sd[t] - s;
#pragma unroll
  for (int k = 0; k < 8; ++k) {
    if (base + k < n) out[base + k] = run;
    run += v[k];
  }
  if (t == 255) bsum[blockIdx.x] = sd[255];
}

// merged scanB+scanC: block b adds sum(bsum[0..b)) to its 2048-range
__global__ void scanBC(int* __restrict__ out, const int* __restrict__ bsum,
                       int NBs, int n) {
  __shared__ int sd[256];
  int t = threadIdx.x, b = blockIdx.x;
  sd[t] = (t < NBs && t < b) ? bsum[t] : 0;
  __syncthreads();
  for (int d = 128; d > 0; d >>= 1) {
    if (t < d) sd[t] += sd[t + d];
    __syncthreads();
  }
  int add = sd[0];
  if (add == 0) return;
  int base = b * 2048 + t * 8;
#pragma unroll
  for (int k = 0; k < 8; ++k)
    if (base + k < n) out[base + k] += add;
}

// ---------------- pass 1b: scatter packed records into coarse buckets ----------------
__global__ void p1scatter(const int* __restrict__ src, const int* __restrict__ dst, int E,
                          int NBK, int SCN, const int* __restrict__ H2,
                          uint* __restrict__ ebuf, uchar* __restrict__ sbuf) {
  __shared__ int cd[512], cs[512];
  int t = threadIdx.x, b = blockIdx.x;
  for (int k = t; k < NBK; k += 512) {
    cd[k] = H2[k * G1 + b];
    cs[k] = H2[SCN + k * G1 + b] - E;
  }
  __syncthreads();
  int chunk = (((E + G1 - 1) / G1) + 3) & ~3;
  int c0 = b * chunk, c1 = min(E, c0 + chunk);
  int e = c0 + t * 4;
  for (; e + 3 < c1; e += 2048) {
    int4 dv = *(const int4*)(dst + e);
    int4 sv = *(const int4*)(src + e);
#pragma unroll
    for (int k = 0; k < 4; ++k) {
      int d = (&dv.x)[k], s = (&sv.x)[k];
      int p = atomicAdd(&cd[d >> SH], 1);
      ebuf[p] = ((uint)s << 8) | (uint)(d & 255);
      int q = atomicAdd(&cs[s >> SH], 1);
      sbuf[q] = (uchar)(s & 255);
    }
  }
  for (; e < c1; ++e) {
    int d = dst[e], s = src[e];
    int p = atomicAdd(&cd[d >> SH], 1);
    ebuf[p] = ((uint)s << 8) | (uint)(d & 255);
    int q = atomicAdd(&cs[s >> SH], 1);
    sbuf[q] = (uchar)(s & 255);
  }
}

// ---------------- pass 2: split src-side / dst-side across 2*NBK blocks ----------------
__global__ void p2build(const uint* __restrict__ ebuf, const uchar* __restrict__ sbuf,
                        const int* __restrict__ H2, int E, int N, int NBK, int SCN,
                        int* __restrict__ offsets, int* __restrict__ csr,
                        float* __restrict__ out_norm, float* __restrict__ in_norm) {
  __shared__ int cnt[256], sd[256], cur[256];
  int t = threadIdx.x, b = blockIdx.x;
  if (b >= NBK) {
    int buck = b - NBK;
    int base = buck << SH;
    int sbase = H2[SCN + buck * G1] - E;
    int send = (buck == NBK - 1) ? E : (H2[SCN + (buck + 1) * G1] - E);
    cnt[t] = 0;
    __syncthreads();
    for (int i = sbase + t; i < send; i += 256) atomicAdd(&cnt[sbuf[i]], 1);
    __syncthreads();
    if (base + t < N) out_norm[base + t] = cnt[t] > 0 ? rsqrtf((float)cnt[t]) : 0.f;
    return;
  }
  int buck = b;
  int base = buck << SH;
  int dbase = H2[buck * G1];
  int dend = (buck == NBK - 1) ? E : H2[(buck + 1) * G1];

  cnt[t] = 0;
  __syncthreads();
  for (int i = dbase + t; i < dend; i += 256) atomicAdd(&cnt[ebuf[i] & 255u], 1);
  __syncthreads();
  int v = cnt[t];
  sd[t] = v;
  __syncthreads();
  for (int d = 1; d < 256; d <<= 1) {
    int tmp = (t >= d) ? sd[t - d] : 0;
    __syncthreads();
    if (t >= d) sd[t] += tmp;
    __syncthreads();
  }
  int excl = sd[t] - v;
  if (base + t < N) {
    offsets[base + t] = dbase + excl;
    in_norm[base + t] = v > 0 ? rsqrtf((float)v) : 0.f;
  }
  if (buck == NBK - 1 && t == 0) offsets[N] = E;
  cur[t] = dbase + excl;
  __syncthreads();
  for (int i = dbase + t; i < dend; i += 256) {
    uint r = ebuf[i];
    int p = atomicAdd(&cur[r & 255u], 1);
    csr[p] = (int)(r >> 8);
  }
}

// ---------------- layer GEMM: y = diag(norm)*(x@W) [+ z' = x@WoSlab] ----------------
// Operand-swapped MFMA; uint2 packed stores. ZMODE 0: y only (8 tiles).
// ZMODE 1: + z' init (12 tiles). ZMODE 2: + z' accumulate.
// Pad rows (r>=N) written ZERO everywhere.
template <bool FP32A, int ZMODE>
__global__ __launch_bounds__(256)
void gemm_layer(const void* __restrict__ xv, int N,
                const ushort* __restrict__ wt, const ushort* __restrict__ wz,
                ushort* __restrict__ y, const float* __restrict__ onorm,
                ushort* __restrict__ zp) {
  constexpr int NT = ZMODE ? 12 : 8;
  __shared__ ushort Bs[NT * 2048];
  const int tid = threadIdx.x;
  const int row0 = blockIdx.x * 128;
  const int w = tid >> 6, l = tid & 63;
  const int lr = l & 15, lg = l >> 4;

  bf16x8 a[2][4];
  if constexpr (FP32A) {
    const float* xf = (const float*)xv;
#pragma unroll
    for (int mt = 0; mt < 2; ++mt)
#pragma unroll
      for (int kk = 0; kk < 4; ++kk) {
        int row = row0 + w * 32 + mt * 16 + lr;
        if (row >= N) row = N - 1;   // clamp: input has exactly N rows
        const float* p = xf + (size_t)row * 128 + kk * 32 + lg * 8;
        float4 f0 = *(const float4*)p;
        float4 f1 = *(const float4*)(p + 4);
        union { ushort us[8]; bf16x8 v; } tv;
        tv.us[0] = f2b(f0.x); tv.us[1] = f2b(f0.y);
        tv.us[2] = f2b(f0.z); tv.us[3] = f2b(f0.w);
        tv.us[4] = f2b(f1.x); tv.us[5] = f2b(f1.y);
        tv.us[6] = f2b(f1.z); tv.us[7] = f2b(f1.w);
        a[mt][kk] = tv.v;
      }
  } else {
    const ushort* xb = (const ushort*)xv;
#pragma unroll
    for (int mt = 0; mt < 2; ++mt)
#pragma unroll
      for (int kk = 0; kk < 4; ++kk) {
        int row = row0 + w * 32 + mt * 16 + lr;
        a[mt][kk] = *(const bf16x8*)&xb[(size_t)row * 128 + kk * 32 + lg * 8];
      }
  }

#pragma unroll
  for (int it = 0; it < 8; ++it)
    gload_lds16(wt + it * 2048 + tid * 8, &Bs[it * 2048 + tid * 8]);
  if constexpr (ZMODE) {
#pragma unroll
    for (int it = 0; it < 4; ++it)
      gload_lds16(wz + it * 2048 + tid * 8, &Bs[(8 + it) * 2048 + tid * 8]);
  }
  __syncthreads();

  f32x4 acc[2][NT];
#pragma unroll
  for (int mt = 0; mt < 2; ++mt)
#pragma unroll
    for (int nt = 0; nt < NT; ++nt) acc[mt][nt] = (f32x4)0.f;

#pragma unroll
  for (int nt = 0; nt < NT; ++nt) {
    bf16x8 bw[4];
#pragma unroll
    for (int kk = 0; kk < 4; ++kk) {
      int row = nt * 16 + lr;
      bw[kk] = *(const bf16x8*)&Bs[row * 128 + ((kk * 32 + lg * 8) ^ ((row & 7) << 3))];
    }
#pragma unroll
    for (int mt = 0; mt < 2; ++mt)
#pragma unroll
      for (int kk = 0; kk < 4; ++kk)
        acc[mt][nt] = __builtin_amdgcn_mfma_f32_16x16x32_bf16(bw[kk], a[mt][kk], acc[mt][nt], 0, 0, 0);
  }

#pragma unroll
  for (int mt = 0; mt < 2; ++mt) {
    int r = row0 + w * 32 + mt * 16 + lr;
    bool live = (r < N);
    float s = live ? onorm[r] : 0.f;
#pragma unroll
    for (int nt = 0; nt < 8; ++nt) {
      uint2 o;
      if (live) {
        o.x = (uint)f2b(acc[mt][nt][0] * s) | ((uint)f2b(acc[mt][nt][1] * s) << 16);
        o.y = (uint)f2b(acc[mt][nt][2] * s) | ((uint)f2b(acc[mt][nt][3] * s) << 16);
      } else { o.x = 0; o.y = 0; }
      *(uint2*)&y[(size_t)r * 128 + nt * 16 + lg * 4] = o;
    }
    if constexpr (ZMODE) {
#pragma unroll
      for (int nt = 8; nt < 12; ++nt) {
        int zcol = (nt - 8) * 16 + lg * 4;
        ushort* zpp = zp + (size_t)r * 64 + zcol;
        uint2 o;
        if (live) {
          float v0 = acc[mt][nt][0], v1 = acc[mt][nt][1];
          float v2 = acc[mt][nt][2], v3 = acc[mt][nt][3];
          if constexpr (ZMODE == 2) {
            uint2 old = *(const uint2*)zpp;
            v0 += b2f(old.x & 0xffff); v1 += b2f(old.x >> 16);
            v2 += b2f(old.y & 0xffff); v3 += b2f(old.y >> 16);
          }
          o.x = (uint)f2b(v0) | ((uint)f2b(v1) << 16);
          o.y = (uint)f2b(v2) | ((uint)f2b(v3) << 16);
        } else { o.x = 0; o.y = 0; }
        *(uint2*)zpp = o;
      }
    }
  }
}

#define ACCV(v) { a2[0] += up2(v.x); a2[1] += up2(v.y); a2[2] += up2(v.z); a2[3] += up2(v.w); }

// ---------------- aggregation: one wave per node, 4 edge-groups x 16 lanes ----------------
__global__ void agg_kernel(const ushort* __restrict__ y, uint* __restrict__ h,
                           const int* __restrict__ csr, const int* __restrict__ offsets,
                           const float* __restrict__ in_norm, const float* __restrict__ bias,
                           int N) {
  int node = blockIdx.x * 4 + (threadIdx.x >> 6);
  if (node >= N) return;
  const int l = threadIdx.x & 63;
  const int g = l >> 4;
  const int q = l & 15;
  const uint4* yp = (const uint4*)y;   // 16 uint4 per row
  int off = offsets[node], end = offsets[node + 1];
  f32x2 a2[4];
#pragma unroll
  for (int k = 0; k < 4; ++k) a2[k] = (f32x2)0.f;

  int i = off;
  for (; i + 16 <= end; i += 16) {
    int s0 = csr[i + g];
    int s1 = csr[i + 4 + g];
    int s2 = csr[i + 8 + g];
    int s3 = csr[i + 12 + g];
    uint4 v0 = yp[(size_t)s0 * 16 + q];
    uint4 v1 = yp[(size_t)s1 * 16 + q];
    uint4 v2 = yp[(size_t)s2 * 16 + q];
    uint4 v3 = yp[(size_t)s3 * 16 + q];
    ACCV(v0) ACCV(v1) ACCV(v2) ACCV(v3)
  }
  for (; i < end; i += 4) {
    int idx = i + g;
    int s = (idx < end) ? csr[min(idx, end - 1)] : N;  // row N is all-zero
    uint4 v = yp[(size_t)s * 16 + q];
    ACCV(v)
  }
#pragma unroll
  for (int k = 0; k < 4; ++k) {
    a2[k].x += __shfl_xor(a2[k].x, 16);
    a2[k].y += __shfl_xor(a2[k].y, 16);
    a2[k].x += __shfl_xor(a2[k].x, 32);
    a2[k].y += __shfl_xor(a2[k].y, 32);
  }
  if (g == 0) {
    float s = in_norm[node];
    float4 b0 = *(const float4*)(bias + 8 * q);
    float4 b1 = *(const float4*)(bias + 8 * q + 4);
    float r0 = fmaxf(fmaf(a2[0].x, s, b0.x), 0.f);
    float r1 = fmaxf(fmaf(a2[0].y, s, b0.y), 0.f);
    float r2 = fmaxf(fmaf(a2[1].x, s, b0.z), 0.f);
    float r3 = fmaxf(fmaf(a2[1].y, s, b0.w), 0.f);
    float r4 = fmaxf(fmaf(a2[2].x, s, b1.x), 0.f);
    float r5 = fmaxf(fmaf(a2[2].y, s, b1.y), 0.f);
    float r6 = fmaxf(fmaf(a2[3].x, s, b1.z), 0.f);
    float r7 = fmaxf(fmaf(a2[3].y, s, b1.w), 0.f);
    uint4 o;
    o.x = (uint)f2b(r0) | ((uint)f2b(r1) << 16);
    o.y = (uint)f2b(r2) | ((uint)f2b(r3) << 16);
    o.z = (uint)f2b(r4) | ((uint)f2b(r5) << 16);
    o.w = (uint)f2b(r6) | ((uint)f2b(r7) << 16);
    ((uint4*)h)[(size_t)node * 16 + q] = o;
  }
}

// ---------------- agg_final: layer-3 aggregation fused with zbb = h3@Wo3 + z' ----------------
// Per block: 4 nodes (1/wave). Gather+reduce h3 rows -> LDS 16x128 bf16 tile
// (rows 4..15 zero) -> each wave does 4 MFMAs vs Wz3 (its 16-col tile) ->
// zbb[node] = C + z'. h3 never touches global memory.
__global__ __launch_bounds__(256)
void agg_final(const ushort* __restrict__ y, const ushort* __restrict__ zp,
               const ushort* __restrict__ wz3, ushort* __restrict__ zbb,
               const int* __restrict__ csr, const int* __restrict__ offsets,
               const float* __restrict__ in_norm, const float* __restrict__ bias,
               int N) {
  __shared__ ushort h3t[16 * 128];
  const int t = threadIdx.x;
  const int wv = t >> 6;
  const int base = blockIdx.x * 4;
  const int node = base + wv;
  const int l = t & 63;
  const int g = l >> 4;
  const int q = l & 15;
  const int lr = l & 15, lg = l >> 4;

  ((uint*)h3t)[t] = 0;
  ((uint*)h3t)[t + 256] = 0;
  __syncthreads();

  const bool valid = (node < N);
  int off = 0, end = 0;
  if (valid) { off = offsets[node]; end = offsets[node + 1]; }
  const uint4* yp = (const uint4*)y;
  f32x2 a2[4];
#pragma unroll
  for (int k = 0; k < 4; ++k) a2[k] = (f32x2)0.f;

  int i = off;
  for (; i + 16 <= end; i += 16) {
    int s0 = csr[i + g];
    int s1 = csr[i + 4 + g];
    int s2 = csr[i + 8 + g];
    int s3 = csr[i + 12 + g];
    uint4 v0 = yp[(size_t)s0 * 16 + q];
    uint4 v1 = yp[(size_t)s1 * 16 + q];
    uint4 v2 = yp[(size_t)s2 * 16 + q];
    uint4 v3 = yp[(size_t)s3 * 16 + q];
    ACCV(v0) ACCV(v1) ACCV(v2) ACCV(v3)
  }
  for (; i < end; i += 4) {
    int idx = i + g;
    int s = (idx < end) ? csr[min(idx, end - 1)] : N;
    uint4 v = yp[(size_t)s * 16 + q];
    ACCV(v)
  }
#pragma unroll
  for (int k = 0; k < 4; ++k) {
    a2[k].x += __shfl_xor(a2[k].x, 16);
    a2[k].y += __shfl_xor(a2[k].y, 16);
    a2[k].x += __shfl_xor(a2[k].x, 32);
    a2[k].y += __shfl_xor(a2[k].y, 32);
  }
  if (valid && l < 16) {
    float s = in_norm[node];
    float4 b0 = *(const float4*)(bias + 8 * l);
    float4 b1 = *(const float4*)(bias + 8 * l + 4);
    float r0 = fmaxf(fmaf(a2[0].x, s, b0.x), 0.f);
    float r1 = fmaxf(fmaf(a2[0].y, s, b0.y), 0.f);
    float r2 = fmaxf(fmaf(a2[1].x, s, b0.z), 0.f);
    float r3 = fmaxf(fmaf(a2[1].y, s, b0.w), 0.f);
    float r4 = fmaxf(fmaf(a2[2].x, s, b1.x), 0.f);
    float r5 = fmaxf(fmaf(a2[2].y, s, b1.y), 0.f);
    float r6 = fmaxf(fmaf(a2[3].x, s, b1.z), 0.f);
    float r7 = fmaxf(fmaf(a2[3].y, s, b1.w), 0.f);
    uint4 o;
    o.x = (uint)f2b(r0) | ((uint)f2b(r1) << 16);
    o.y = (uint)f2b(r2) | ((uint)f2b(r3) << 16);
    o.z = (uint)f2b(r4) | ((uint)f2b(r5) << 16);
    o.w = (uint)f2b(r6) | ((uint)f2b(r7) << 16);
    ((uint4*)h3t)[wv * 16 + l] = o;
  }
  __syncthreads();

  // MFMA: wave wv computes output cols [wv*16, wv*16+16)
  bf16x8 af[4], bf[4];
#pragma unroll
  for (int kk = 0; kk < 4; ++kk) {
    af[kk] = *(const bf16x8*)&h3t[lr * 128 + kk * 32 + lg * 8];
    bf[kk] = *(const bf16x8*)&wz3[(size_t)(wv * 16 + lr) * 128 + kk * 32 + lg * 8];
  }
  f32x4 acc = (f32x4)0.f;
#pragma unroll
  for (int kk = 0; kk < 4; ++kk)
    acc = __builtin_amdgcn_mfma_f32_16x16x32_bf16(af[kk], bf[kk], acc, 0, 0, 0);

  if (lg == 0) {
#pragma unroll
    for (int j = 0; j < 4; ++j) {
      int nd = base + j;
      if (nd <= N) {   // row N: acc=0, zp row N = 0 -> stores 0 (pool tail zero row)
        int col = wv * 16 + lr;
        float v = acc[j] + b2f(zp[(size_t)nd * 64 + col]);
        zbb[(size_t)nd * 64 + col] = f2b(v);
      }
    }
  }
}

// ---------------- pooling: one wave per node, 8 edge-groups x 8 lanes ----------------
__global__ void pool_kernel(const ushort* __restrict__ zb, float* __restrict__ out,
                            const int* __restrict__ csr, const int* __restrict__ offsets,
                            const float* __restrict__ bo, int N) {
  int node = blockIdx.x * 4 + (threadIdx.x >> 6);
  if (node >= N) return;
  const int l = threadIdx.x & 63;
  const int g = l >> 3;
  const int q = l & 7;
  const uint4* zp = (const uint4*)zb;  // 8 uint4 per row
  int off = offsets[node], end = offsets[node + 1];
  f32x2 a2[4];
#pragma unroll
  for (int k = 0; k < 4; ++k) a2[k] = (f32x2)0.f;

  int i = off;
  for (; i + 16 <= end; i += 16) {
    int s0 = csr[i + g];
    int s1 = csr[i + 8 + g];
    uint4 v0 = zp[(size_t)s0 * 8 + q];
    uint4 v1 = zp[(size_t)s1 * 8 + q];
    ACCV(v0) ACCV(v1)
  }
  for (; i < end; i += 8) {
    int idx = i + g;
    int s = (idx < end) ? csr[min(idx, end - 1)] : N;  // row N is all-zero
    uint4 v = zp[(size_t)s * 8 + q];
    ACCV(v)
  }
#pragma unroll
  for (int k = 0; k < 4; ++k) {
    a2[k].x += __shfl_xor(a2[k].x, 8);
    a2[k].y += __shfl_xor(a2[k].y, 8);
    a2[k].x += __shfl_xor(a2[k].x, 16);
    a2[k].y += __shfl_xor(a2[k].y, 16);
    a2[k].x += __shfl_xor(a2[k].x, 32);
    a2[k].y += __shfl_xor(a2[k].y, 32);
  }
  if (g == 0) {
    float4 o0, o1;
    o0.x = a2[0].x + bo[8 * q + 0];
    o0.y = a2[0].y + bo[8 * q + 1];
    o0.z = a2[1].x + bo[8 * q + 2];
    o0.w = a2[1].y + bo[8 * q + 3];
    o1.x = a2[2].x + bo[8 * q + 4];
    o1.y = a2[2].y + bo[8 * q + 5];
    o1.z = a2[3].x + bo[8 * q + 6];
    o1.w = a2[3].y + bo[8 * q + 7];
    float* op = out + (size_t)node * 64 + 8 * q;
    *(float4*)op = o0;
    *(float4*)(op + 4) = o1;
  }
}

extern "C" void kernel_launch(void* const* d_in, const int* in_sizes, int n_in,
                              void* d_out, int out_size, void* d_ws, size_t ws_size,
                              hipStream_t stream) {
  const float* feats = (const float*)d_in[0];
  const int* src = (const int*)d_in[1];
  const int* dst = (const int*)d_in[2];
  const float* W0 = (const float*)d_in[3];
  const float* b0 = (const float*)d_in[4];
  const float* W1 = (const float*)d_in[5];
  const float* b1 = (const float*)d_in[6];
  const float* W2 = (const float*)d_in[7];
  const float* b2 = (const float*)d_in[8];
  const float* Wo = (const float*)d_in[9];
  const float* bo = (const float*)d_in[10];
  float* out = (float*)d_out;

  const int N = in_sizes[0] / 128;
  const int E = in_sizes[1];
  const int NP = (N + 1 + 127) & ~127;   // >= N+1: row N is the zero row
  const int NBK = (N + 255) >> SH;
  const int SCN = NBK * G1;
  const int SCN2 = 2 * SCN;

  char* p = (char*)d_ws;
  auto take = [&](size_t bytes) { char* q = p; p += (bytes + 255) & ~(size_t)255; return q; };
  char*  yregion = take((size_t)NP * 128 * 2);         // build temps -> y
  ushort* ybuf = (ushort*)yregion;
  uint*  ebuf  = (uint*)yregion;                       // E*4
  uchar* sbuf  = (uchar*)(yregion + (size_t)E * 4);    // E*1
  int*   H     = (int*)(yregion + (size_t)E * 5 + 256);// SCN2*4
  int*   H2    = H + SCN2;                             // SCN2*4
  ushort* h1   = (ushort*)take((size_t)NP * 128 * 2);
  ushort* h2   = (ushort*)take((size_t)NP * 128 * 2);
  ushort* zp   = (ushort*)take((size_t)NP * 64 * 2);   // z' = h1@Wo1 + h2@Wo2
  ushort* zbb  = (ushort*)take((size_t)NP * 64 * 2);   // final z (pool gather table)
  ushort* Wt1 = (ushort*)take((size_t)128 * 128 * 2);
  ushort* Wt2 = (ushort*)take((size_t)128 * 128 * 2);
  ushort* Wt3 = (ushort*)take((size_t)128 * 128 * 2);
  ushort* Wz1 = (ushort*)take((size_t)64 * 128 * 2);
  ushort* Wz2 = (ushort*)take((size_t)64 * 128 * 2);
  ushort* Wz3 = (ushort*)take((size_t)64 * 128 * 2);
  float* out_norm = (float*)take((size_t)N * 4);
  float* in_norm  = (float*)take((size_t)N * 4);
  int* offsets    = (int*)take((size_t)(N + 1) * 4);
  int* blocksums  = (int*)take(1024);
  int* csr        = (int*)take((size_t)E * 4);
  (void)ws_size; (void)n_in; (void)out_size;

  // ---- graph build (no global atomics) + folded weight prep ----
  p1hist<<<G1 + 72, 512, 0, stream>>>(src, dst, E, NBK, SCN, H,
                                      W0, W1, W2, Wo, Wt1, Wt2, Wt3, Wz1, Wz2, Wz3);
  int NBs = (SCN2 + 2047) / 2048;
  scanA<<<NBs, 256, 0, stream>>>(H, SCN2, H2, blocksums);
  scanBC<<<NBs, 256, 0, stream>>>(H2, blocksums, NBs, SCN2);
  p1scatter<<<G1, 512, 0, stream>>>(src, dst, E, NBK, SCN, H2, ebuf, sbuf);
  p2build<<<2 * NBK, 256, 0, stream>>>(ebuf, sbuf, H2, E, N, NBK, SCN,
                                       offsets, csr, out_norm, in_norm);

  dim3 blk(256);
  int rb = NP / 128;
  int ab = (N + 3) / 4;

  gemm_layer<true, 0><<<rb, blk, 0, stream>>>(feats, N, Wt1, nullptr, ybuf, out_norm, nullptr);
  agg_kernel<<<ab, blk, 0, stream>>>(ybuf, (uint*)h1, csr, offsets, in_norm, b0, N);
  gemm_layer<false, 1><<<rb, blk, 0, stream>>>(h1, N, Wt2, Wz1, ybuf, out_norm, zp);
  agg_kernel<<<ab, blk, 0, stream>>>(ybuf, (uint*)h2, csr, offsets, in_norm, b1, N);
  gemm_layer<false, 2><<<rb, blk, 0, stream>>>(h2, N, Wt3, Wz2, ybuf, out_norm, zp);
  agg_final<<<(N + 4) / 4, blk, 0, stream>>>(ybuf, zp, Wz3, zbb, csr, offsets, in_norm, b2, N);
  pool_kernel<<<ab, blk, 0, stream>>>(zbb, out, csr, offsets, bo, N);
}

// Round 12
// 356.094 us; speedup vs baseline: 1.0981x; 1.0981x over previous
//
#include <hip/hip_runtime.h>

typedef unsigned int uint;
typedef unsigned short ushort;
typedef unsigned char uchar;
typedef __bf16 bf16x8 __attribute__((ext_vector_type(8)));
typedef float f32x4 __attribute__((ext_vector_type(4)));
typedef float f32x2 __attribute__((ext_vector_type(2)));

#define G1 256          // pass-1 blocks
#define SH 8            // 256 nodes per coarse bucket

__device__ __forceinline__ ushort f2b(float f) {
  union { float f; uint u; } x; x.f = f;
  uint r = x.u + 0x7fff + ((x.u >> 16) & 1);
  return (ushort)(r >> 16);
}
__device__ __forceinline__ float b2f(uint s) {
  union { uint u; float f; } x; x.u = s << 16;
  return x.f;
}

// unpack 2 bf16 packed in a uint -> float2
__device__ __forceinline__ f32x2 up2(uint u) {
  union { uint u; float f; } lo, hi;
  lo.u = u << 16;
  hi.u = u & 0xffff0000u;
  f32x2 r; r.x = lo.f; r.y = hi.f;
  return r;
}

__device__ __forceinline__ void gload_lds16(const void* g, void* l) {
  __builtin_amdgcn_global_load_lds(
      (const __attribute__((address_space(1))) void*)g,
      (__attribute__((address_space(3))) void*)l, 16, 0, 0);
}

// ---------------- pass 1a: histograms (x2 replicated) + folded weight prep ----------------
// Blocks [0,G1): histogram (512 thr). Blocks [G1,G1+72): weight prep (8 rids/block).
__global__ void p1hist(const int* __restrict__ src, const int* __restrict__ dst, int E,
                       int NBK, int SCN, int* __restrict__ H,
                       const float* __restrict__ W0, const float* __restrict__ W1,
                       const float* __restrict__ W2, const float* __restrict__ Wo,
                       ushort* __restrict__ Wt1, ushort* __restrict__ Wt2,
                       ushort* __restrict__ Wt3, ushort* __restrict__ Wz1,
                       ushort* __restrict__ Wz2, ushort* __restrict__ Wz3) {
  int t = threadIdx.x, b = blockIdx.x;
  if (b >= G1) {
    int rid = (b - G1) * 8 + (t >> 6);   // 0..575
    int tl = t & 63;
    if (rid < 384) {
      ushort* dstp; const float* W; int row;
      if (rid < 128)      { dstp = Wt1; W = W0; row = rid; }
      else if (rid < 256) { dstp = Wt2; W = W1; row = rid - 128; }
      else                { dstp = Wt3; W = W2; row = rid - 256; }
#pragma unroll
      for (int kk = 0; kk < 2; ++kk) {
        int k = tl + kk * 64;
        dstp[row * 128 + (k ^ ((row & 7) << 3))] = f2b(W[(size_t)k * 128 + row]);
      }
    } else {
      // Wz1/Wz2/Wz3: [64][128] swizzled slabs of Wo (cols of Wo as rows)
      ushort* dstp = (rid < 448) ? Wz1 : (rid < 512) ? Wz2 : Wz3;
      int row = (rid - 384) & 63;
      int kbase = ((rid - 384) >> 6) * 128;
#pragma unroll
      for (int kk = 0; kk < 2; ++kk) {
        int k = tl + kk * 64;
        dstp[row * 128 + (k ^ ((row & 7) << 3))] = f2b(Wo[(size_t)(kbase + k) * 64 + row]);
      }
    }
    return;
  }
  __shared__ int hd[2][512], hs[2][512];
  hd[0][t] = 0; hd[1][t] = 0; hs[0][t] = 0; hs[1][t] = 0;
  __syncthreads();
  int rep = t & 1;
  int chunk = (((E + G1 - 1) / G1) + 3) & ~3;
  int c0 = b * chunk, c1 = min(E, c0 + chunk);
  int e = c0 + t * 4;
  for (; e + 3 < c1; e += 2048) {
    int4 dv = *(const int4*)(dst + e);
    int4 sv = *(const int4*)(src + e);
    atomicAdd(&hd[rep][dv.x >> SH], 1); atomicAdd(&hd[rep][dv.y >> SH], 1);
    atomicAdd(&hd[rep][dv.z >> SH], 1); atomicAdd(&hd[rep][dv.w >> SH], 1);
    atomicAdd(&hs[rep][sv.x >> SH], 1); atomicAdd(&hs[rep][sv.y >> SH], 1);
    atomicAdd(&hs[rep][sv.z >> SH], 1); atomicAdd(&hs[rep][sv.w >> SH], 1);
  }
  for (; e < c1; ++e) {
    atomicAdd(&hd[rep][dst[e] >> SH], 1);
    atomicAdd(&hs[rep][src[e] >> SH], 1);
  }
  __syncthreads();
  for (int k = t; k < NBK; k += 512) {
    H[k * G1 + b] = hd[0][k] + hd[1][k];
    H[SCN + k * G1 + b] = hs[0][k] + hs[1][k];
  }
}

// ---------------- scan: per-block scan + blocksum ----------------
__global__ void scanA(const int* __restrict__ in, int n, int* __restrict__ out,
                      int* __restrict__ bsum) {
  __shared__ int sd[256];
  int t = threadIdx.x;
  int base = blockIdx.x * 2048 + t * 8;
  int v[8]; int s = 0;
#pragma unroll
  for (int k = 0; k < 8; ++k) { v[k] = (base + k < n) ? in[base + k] : 0; s += v[k]; }
  sd[t] = s;
  __syncthreads();
  for (int d = 1; d < 256; d <<= 1) {
    int tmp = (t >= d) ? sd[t - d] : 0;
    __syncthreads();
    if (t >= d) sd[t] += tmp;
    __syncthreads();
  }
  int run = sd[t] - s;
#pragma unroll
  for (int k = 0; k < 8; ++k) {
    if (base + k < n) out[base + k] = run;
    run += v[k];
  }
  if (t == 255) bsum[blockIdx.x] = sd[255];
}

// merged scanB+scanC: block b adds sum(bsum[0..b)) to its 2048-range
__global__ void scanBC(int* __restrict__ out, const int* __restrict__ bsum,
                       int NBs, int n) {
  __shared__ int sd[256];
  int t = threadIdx.x, b = blockIdx.x;
  sd[t] = (t < NBs && t < b) ? bsum[t] : 0;
  __syncthreads();
  for (int d = 128; d > 0; d >>= 1) {
    if (t < d) sd[t] += sd[t + d];
    __syncthreads();
  }
  int add = sd[0];
  if (add == 0) return;
  int base = b * 2048 + t * 8;
#pragma unroll
  for (int k = 0; k < 8; ++k)
    if (base + k < n) out[base + k] += add;
}

// ---------------- pass 1b: scatter packed records into coarse buckets ----------------
__global__ void p1scatter(const int* __restrict__ src, const int* __restrict__ dst, int E,
                          int NBK, int SCN, const int* __restrict__ H2,
                          uint* __restrict__ ebuf, uchar* __restrict__ sbuf) {
  __shared__ int cd[512], cs[512];
  int t = threadIdx.x, b = blockIdx.x;
  for (int k = t; k < NBK; k += 512) {
    cd[k] = H2[k * G1 + b];
    cs[k] = H2[SCN + k * G1 + b] - E;
  }
  __syncthreads();
  int chunk = (((E + G1 - 1) / G1) + 3) & ~3;
  int c0 = b * chunk, c1 = min(E, c0 + chunk);
  int e = c0 + t * 4;
  for (; e + 3 < c1; e += 2048) {
    int4 dv = *(const int4*)(dst + e);
    int4 sv = *(const int4*)(src + e);
#pragma unroll
    for (int k = 0; k < 4; ++k) {
      int d = (&dv.x)[k], s = (&sv.x)[k];
      int p = atomicAdd(&cd[d >> SH], 1);
      ebuf[p] = ((uint)s << 8) | (uint)(d & 255);
      int q = atomicAdd(&cs[s >> SH], 1);
      sbuf[q] = (uchar)(s & 255);
    }
  }
  for (; e < c1; ++e) {
    int d = dst[e], s = src[e];
    int p = atomicAdd(&cd[d >> SH], 1);
    ebuf[p] = ((uint)s << 8) | (uint)(d & 255);
    int q = atomicAdd(&cs[s >> SH], 1);
    sbuf[q] = (uchar)(s & 255);
  }
}

// ---------------- pass 2: split src-side / dst-side across 2*NBK blocks ----------------
__global__ void p2build(const uint* __restrict__ ebuf, const uchar* __restrict__ sbuf,
                        const int* __restrict__ H2, int E, int N, int NBK, int SCN,
                        int* __restrict__ offsets, int* __restrict__ csr,
                        float* __restrict__ out_norm, float* __restrict__ in_norm) {
  __shared__ int cnt[256], sd[256], cur[256];
  int t = threadIdx.x, b = blockIdx.x;
  if (b >= NBK) {
    int buck = b - NBK;
    int base = buck << SH;
    int sbase = H2[SCN + buck * G1] - E;
    int send = (buck == NBK - 1) ? E : (H2[SCN + (buck + 1) * G1] - E);
    cnt[t] = 0;
    __syncthreads();
    for (int i = sbase + t; i < send; i += 256) atomicAdd(&cnt[sbuf[i]], 1);
    __syncthreads();
    if (base + t < N) out_norm[base + t] = cnt[t] > 0 ? rsqrtf((float)cnt[t]) : 0.f;
    return;
  }
  int buck = b;
  int base = buck << SH;
  int dbase = H2[buck * G1];
  int dend = (buck == NBK - 1) ? E : H2[(buck + 1) * G1];

  cnt[t] = 0;
  __syncthreads();
  for (int i = dbase + t; i < dend; i += 256) atomicAdd(&cnt[ebuf[i] & 255u], 1);
  __syncthreads();
  int v = cnt[t];
  sd[t] = v;
  __syncthreads();
  for (int d = 1; d < 256; d <<= 1) {
    int tmp = (t >= d) ? sd[t - d] : 0;
    __syncthreads();
    if (t >= d) sd[t] += tmp;
    __syncthreads();
  }
  int excl = sd[t] - v;
  if (base + t < N) {
    offsets[base + t] = dbase + excl;
    in_norm[base + t] = v > 0 ? rsqrtf((float)v) : 0.f;
  }
  if (buck == NBK - 1 && t == 0) offsets[N] = E;
  cur[t] = dbase + excl;
  __syncthreads();
  for (int i = dbase + t; i < dend; i += 256) {
    uint r = ebuf[i];
    int p = atomicAdd(&cur[r & 255u], 1);
    csr[p] = (int)(r >> 8);
  }
}

// ---------------- layer GEMM: y = diag(norm)*(x@W) [+ z' = x@WoSlab] ----------------
// Operand-swapped MFMA; uint2 packed stores. ZMODE 0: y only (8 tiles).
// ZMODE 1: + z' init (12 tiles). ZMODE 2: + z' accumulate.
// Pad rows (r>=N) written ZERO everywhere.
template <bool FP32A, int ZMODE>
__global__ __launch_bounds__(256)
void gemm_layer(const void* __restrict__ xv, int N,
                const ushort* __restrict__ wt, const ushort* __restrict__ wz,
                ushort* __restrict__ y, const float* __restrict__ onorm,
                ushort* __restrict__ zp) {
  constexpr int NT = ZMODE ? 12 : 8;
  __shared__ ushort Bs[NT * 2048];
  const int tid = threadIdx.x;
  const int row0 = blockIdx.x * 128;
  const int w = tid >> 6, l = tid & 63;
  const int lr = l & 15, lg = l >> 4;

  bf16x8 a[2][4];
  if constexpr (FP32A) {
    const float* xf = (const float*)xv;
#pragma unroll
    for (int mt = 0; mt < 2; ++mt)
#pragma unroll
      for (int kk = 0; kk < 4; ++kk) {
        int row = row0 + w * 32 + mt * 16 + lr;
        if (row >= N) row = N - 1;   // clamp: input has exactly N rows
        const float* p = xf + (size_t)row * 128 + kk * 32 + lg * 8;
        float4 f0 = *(const float4*)p;
        float4 f1 = *(const float4*)(p + 4);
        union { ushort us[8]; bf16x8 v; } tv;
        tv.us[0] = f2b(f0.x); tv.us[1] = f2b(f0.y);
        tv.us[2] = f2b(f0.z); tv.us[3] = f2b(f0.w);
        tv.us[4] = f2b(f1.x); tv.us[5] = f2b(f1.y);
        tv.us[6] = f2b(f1.z); tv.us[7] = f2b(f1.w);
        a[mt][kk] = tv.v;
      }
  } else {
    const ushort* xb = (const ushort*)xv;
#pragma unroll
    for (int mt = 0; mt < 2; ++mt)
#pragma unroll
      for (int kk = 0; kk < 4; ++kk) {
        int row = row0 + w * 32 + mt * 16 + lr;
        a[mt][kk] = *(const bf16x8*)&xb[(size_t)row * 128 + kk * 32 + lg * 8];
      }
  }

#pragma unroll
  for (int it = 0; it < 8; ++it)
    gload_lds16(wt + it * 2048 + tid * 8, &Bs[it * 2048 + tid * 8]);
  if constexpr (ZMODE) {
#pragma unroll
    for (int it = 0; it < 4; ++it)
      gload_lds16(wz + it * 2048 + tid * 8, &Bs[(8 + it) * 2048 + tid * 8]);
  }
  __syncthreads();

  f32x4 acc[2][NT];
#pragma unroll
  for (int mt = 0; mt < 2; ++mt)
#pragma unroll
    for (int nt = 0; nt < NT; ++nt) acc[mt][nt] = (f32x4)0.f;

#pragma unroll
  for (int nt = 0; nt < NT; ++nt) {
    bf16x8 bw[4];
#pragma unroll
    for (int kk = 0; kk < 4; ++kk) {
      int row = nt * 16 + lr;
      bw[kk] = *(const bf16x8*)&Bs[row * 128 + ((kk * 32 + lg * 8) ^ ((row & 7) << 3))];
    }
#pragma unroll
    for (int mt = 0; mt < 2; ++mt)
#pragma unroll
      for (int kk = 0; kk < 4; ++kk)
        acc[mt][nt] = __builtin_amdgcn_mfma_f32_16x16x32_bf16(bw[kk], a[mt][kk], acc[mt][nt], 0, 0, 0);
  }

#pragma unroll
  for (int mt = 0; mt < 2; ++mt) {
    int r = row0 + w * 32 + mt * 16 + lr;
    bool live = (r < N);
    float s = live ? onorm[r] : 0.f;
#pragma unroll
    for (int nt = 0; nt < 8; ++nt) {
      uint2 o;
      if (live) {
        o.x = (uint)f2b(acc[mt][nt][0] * s) | ((uint)f2b(acc[mt][nt][1] * s) << 16);
        o.y = (uint)f2b(acc[mt][nt][2] * s) | ((uint)f2b(acc[mt][nt][3] * s) << 16);
      } else { o.x = 0; o.y = 0; }
      *(uint2*)&y[(size_t)r * 128 + nt * 16 + lg * 4] = o;
    }
    if constexpr (ZMODE) {
#pragma unroll
      for (int nt = 8; nt < 12; ++nt) {
        int zcol = (nt - 8) * 16 + lg * 4;
        ushort* zpp = zp + (size_t)r * 64 + zcol;
        uint2 o;
        if (live) {
          float v0 = acc[mt][nt][0], v1 = acc[mt][nt][1];
          float v2 = acc[mt][nt][2], v3 = acc[mt][nt][3];
          if constexpr (ZMODE == 2) {
            uint2 old = *(const uint2*)zpp;
            v0 += b2f(old.x & 0xffff); v1 += b2f(old.x >> 16);
            v2 += b2f(old.y & 0xffff); v3 += b2f(old.y >> 16);
          }
          o.x = (uint)f2b(v0) | ((uint)f2b(v1) << 16);
          o.y = (uint)f2b(v2) | ((uint)f2b(v3) << 16);
        } else { o.x = 0; o.y = 0; }
        *(uint2*)zpp = o;
      }
    }
  }
}

// ---------------- z3 GEMM: zbb = bf16(h3@Wo3 + z'), K=128, 64 cols ----------------
__global__ __launch_bounds__(256)
void gemm_z3(const ushort* __restrict__ h3, const ushort* __restrict__ zp, int N,
             const ushort* __restrict__ wz, ushort* __restrict__ zbb) {
  __shared__ ushort Bs[4 * 2048];
  const int tid = threadIdx.x;
  const int row0 = blockIdx.x * 128;
  const int w = tid >> 6, l = tid & 63;
  const int lr = l & 15, lg = l >> 4;

  bf16x8 a[2][4];
#pragma unroll
  for (int mt = 0; mt < 2; ++mt)
#pragma unroll
    for (int kk = 0; kk < 4; ++kk) {
      int row = row0 + w * 32 + mt * 16 + lr;
      a[mt][kk] = *(const bf16x8*)&h3[(size_t)row * 128 + kk * 32 + lg * 8];
    }

#pragma unroll
  for (int it = 0; it < 4; ++it)
    gload_lds16(wz + it * 2048 + tid * 8, &Bs[it * 2048 + tid * 8]);
  __syncthreads();

  f32x4 acc[2][4];
#pragma unroll
  for (int mt = 0; mt < 2; ++mt)
#pragma unroll
    for (int nt = 0; nt < 4; ++nt) acc[mt][nt] = (f32x4)0.f;

#pragma unroll
  for (int nt = 0; nt < 4; ++nt) {
    bf16x8 bw[4];
#pragma unroll
    for (int kk = 0; kk < 4; ++kk) {
      int row = nt * 16 + lr;
      bw[kk] = *(const bf16x8*)&Bs[row * 128 + ((kk * 32 + lg * 8) ^ ((row & 7) << 3))];
    }
#pragma unroll
    for (int mt = 0; mt < 2; ++mt)
#pragma unroll
      for (int kk = 0; kk < 4; ++kk)
        acc[mt][nt] = __builtin_amdgcn_mfma_f32_16x16x32_bf16(bw[kk], a[mt][kk], acc[mt][nt], 0, 0, 0);
  }

#pragma unroll
  for (int mt = 0; mt < 2; ++mt) {
    int r = row0 + w * 32 + mt * 16 + lr;
    bool live = (r < N);
#pragma unroll
    for (int nt = 0; nt < 4; ++nt) {
      int col = nt * 16 + lg * 4;
      ushort* zo = zbb + (size_t)r * 64 + col;
      uint2 o;
      if (live) {
        uint2 old = *(const uint2*)&zp[(size_t)r * 64 + col];
        float v0 = acc[mt][nt][0] + b2f(old.x & 0xffff);
        float v1 = acc[mt][nt][1] + b2f(old.x >> 16);
        float v2 = acc[mt][nt][2] + b2f(old.y & 0xffff);
        float v3 = acc[mt][nt][3] + b2f(old.y >> 16);
        o.x = (uint)f2b(v0) | ((uint)f2b(v1) << 16);
        o.y = (uint)f2b(v2) | ((uint)f2b(v3) << 16);
      } else { o.x = 0; o.y = 0; }
      *(uint2*)zo = o;
    }
  }
}

#define ACCV(v) { a2[0] += up2(v.x); a2[1] += up2(v.y); a2[2] += up2(v.z); a2[3] += up2(v.w); }

// ---------------- aggregation: one wave per node, 4 edge-groups x 16 lanes ----------------
__global__ void agg_kernel(const ushort* __restrict__ y, uint* __restrict__ h,
                           const int* __restrict__ csr, const int* __restrict__ offsets,
                           const float* __restrict__ in_norm, const float* __restrict__ bias,
                           int N) {
  int node = blockIdx.x * 4 + (threadIdx.x >> 6);
  if (node >= N) return;
  const int l = threadIdx.x & 63;
  const int g = l >> 4;
  const int q = l & 15;
  const uint4* yp = (const uint4*)y;   // 16 uint4 per row
  int off = offsets[node], end = offsets[node + 1];
  f32x2 a2[4];
#pragma unroll
  for (int k = 0; k < 4; ++k) a2[k] = (f32x2)0.f;

  int i = off;
  for (; i + 16 <= end; i += 16) {
    int s0 = csr[i + g];
    int s1 = csr[i + 4 + g];
    int s2 = csr[i + 8 + g];
    int s3 = csr[i + 12 + g];
    uint4 v0 = yp[(size_t)s0 * 16 + q];
    uint4 v1 = yp[(size_t)s1 * 16 + q];
    uint4 v2 = yp[(size_t)s2 * 16 + q];
    uint4 v3 = yp[(size_t)s3 * 16 + q];
    ACCV(v0) ACCV(v1) ACCV(v2) ACCV(v3)
  }
  for (; i < end; i += 4) {
    int idx = i + g;
    int s = (idx < end) ? csr[min(idx, end - 1)] : N;  // row N is all-zero
    uint4 v = yp[(size_t)s * 16 + q];
    ACCV(v)
  }
#pragma unroll
  for (int k = 0; k < 4; ++k) {
    a2[k].x += __shfl_xor(a2[k].x, 16);
    a2[k].y += __shfl_xor(a2[k].y, 16);
    a2[k].x += __shfl_xor(a2[k].x, 32);
    a2[k].y += __shfl_xor(a2[k].y, 32);
  }
  if (g == 0) {
    float s = in_norm[node];
    float4 b0 = *(const float4*)(bias + 8 * q);
    float4 b1 = *(const float4*)(bias + 8 * q + 4);
    float r0 = fmaxf(fmaf(a2[0].x, s, b0.x), 0.f);
    float r1 = fmaxf(fmaf(a2[0].y, s, b0.y), 0.f);
    float r2 = fmaxf(fmaf(a2[1].x, s, b0.z), 0.f);
    float r3 = fmaxf(fmaf(a2[1].y, s, b0.w), 0.f);
    float r4 = fmaxf(fmaf(a2[2].x, s, b1.x), 0.f);
    float r5 = fmaxf(fmaf(a2[2].y, s, b1.y), 0.f);
    float r6 = fmaxf(fmaf(a2[3].x, s, b1.z), 0.f);
    float r7 = fmaxf(fmaf(a2[3].y, s, b1.w), 0.f);
    uint4 o;
    o.x = (uint)f2b(r0) | ((uint)f2b(r1) << 16);
    o.y = (uint)f2b(r2) | ((uint)f2b(r3) << 16);
    o.z = (uint)f2b(r4) | ((uint)f2b(r5) << 16);
    o.w = (uint)f2b(r6) | ((uint)f2b(r7) << 16);
    ((uint4*)h)[(size_t)node * 16 + q] = o;
  }
}

// ---------------- pooling: one wave per node, 8 edge-groups x 8 lanes ----------------
__global__ void pool_kernel(const ushort* __restrict__ zb, float* __restrict__ out,
                            const int* __restrict__ csr, const int* __restrict__ offsets,
                            const float* __restrict__ bo, int N) {
  int node = blockIdx.x * 4 + (threadIdx.x >> 6);
  if (node >= N) return;
  const int l = threadIdx.x & 63;
  const int g = l >> 3;
  const int q = l & 7;
  const uint4* zp = (const uint4*)zb;  // 8 uint4 per row
  int off = offsets[node], end = offsets[node + 1];
  f32x2 a2[4];
#pragma unroll
  for (int k = 0; k < 4; ++k) a2[k] = (f32x2)0.f;

  int i = off;
  for (; i + 16 <= end; i += 16) {
    int s0 = csr[i + g];
    int s1 = csr[i + 8 + g];
    uint4 v0 = zp[(size_t)s0 * 8 + q];
    uint4 v1 = zp[(size_t)s1 * 8 + q];
    ACCV(v0) ACCV(v1)
  }
  for (; i < end; i += 8) {
    int idx = i + g;
    int s = (idx < end) ? csr[min(idx, end - 1)] : N;  // row N is all-zero
    uint4 v = zp[(size_t)s * 8 + q];
    ACCV(v)
  }
#pragma unroll
  for (int k = 0; k < 4; ++k) {
    a2[k].x += __shfl_xor(a2[k].x, 8);
    a2[k].y += __shfl_xor(a2[k].y, 8);
    a2[k].x += __shfl_xor(a2[k].x, 16);
    a2[k].y += __shfl_xor(a2[k].y, 16);
    a2[k].x += __shfl_xor(a2[k].x, 32);
    a2[k].y += __shfl_xor(a2[k].y, 32);
  }
  if (g == 0) {
    float4 o0, o1;
    o0.x = a2[0].x + bo[8 * q + 0];
    o0.y = a2[0].y + bo[8 * q + 1];
    o0.z = a2[1].x + bo[8 * q + 2];
    o0.w = a2[1].y + bo[8 * q + 3];
    o1.x = a2[2].x + bo[8 * q + 4];
    o1.y = a2[2].y + bo[8 * q + 5];
    o1.z = a2[3].x + bo[8 * q + 6];
    o1.w = a2[3].y + bo[8 * q + 7];
    float* op = out + (size_t)node * 64 + 8 * q;
    *(float4*)op = o0;
    *(float4*)(op + 4) = o1;
  }
}

extern "C" void kernel_launch(void* const* d_in, const int* in_sizes, int n_in,
                              void* d_out, int out_size, void* d_ws, size_t ws_size,
                              hipStream_t stream) {
  const float* feats = (const float*)d_in[0];
  const int* src = (const int*)d_in[1];
  const int* dst = (const int*)d_in[2];
  const float* W0 = (const float*)d_in[3];
  const float* b0 = (const float*)d_in[4];
  const float* W1 = (const float*)d_in[5];
  const float* b1 = (const float*)d_in[6];
  const float* W2 = (const float*)d_in[7];
  const float* b2 = (const float*)d_in[8];
  const float* Wo = (const float*)d_in[9];
  const float* bo = (const float*)d_in[10];
  float* out = (float*)d_out;

  const int N = in_sizes[0] / 128;
  const int E = in_sizes[1];
  const int NP = (N + 1 + 127) & ~127;   // >= N+1: row N is the zero row
  const int NBK = (N + 255) >> SH;
  const int SCN = NBK * G1;
  const int SCN2 = 2 * SCN;

  char* p = (char*)d_ws;
  auto take = [&](size_t bytes) { char* q = p; p += (bytes + 255) & ~(size_t)255; return q; };
  char*  yregion = take((size_t)NP * 128 * 2);         // build temps -> y
  ushort* ybuf = (ushort*)yregion;
  uint*  ebuf  = (uint*)yregion;                       // E*4
  uchar* sbuf  = (uchar*)(yregion + (size_t)E * 4);    // E*1
  int*   H     = (int*)(yregion + (size_t)E * 5 + 256);// SCN2*4
  int*   H2    = H + SCN2;                             // SCN2*4
  ushort* h1   = (ushort*)take((size_t)NP * 128 * 2);  // h1; reused as h3 after gemm2
  ushort* h2   = (ushort*)take((size_t)NP * 128 * 2);
  ushort* zp   = (ushort*)take((size_t)NP * 64 * 2);   // z' = h1@Wo1 + h2@Wo2
  ushort* zbb  = (ushort*)take((size_t)NP * 64 * 2);   // final z (pool gather table)
  ushort* Wt1 = (ushort*)take((size_t)128 * 128 * 2);
  ushort* Wt2 = (ushort*)take((size_t)128 * 128 * 2);
  ushort* Wt3 = (ushort*)take((size_t)128 * 128 * 2);
  ushort* Wz1 = (ushort*)take((size_t)64 * 128 * 2);
  ushort* Wz2 = (ushort*)take((size_t)64 * 128 * 2);
  ushort* Wz3 = (ushort*)take((size_t)64 * 128 * 2);
  float* out_norm = (float*)take((size_t)N * 4);
  float* in_norm  = (float*)take((size_t)N * 4);
  int* offsets    = (int*)take((size_t)(N + 1) * 4);
  int* blocksums  = (int*)take(1024);
  int* csr        = (int*)take((size_t)E * 4);
  (void)ws_size; (void)n_in; (void)out_size;

  // ---- graph build (no global atomics) + folded weight prep ----
  p1hist<<<G1 + 72, 512, 0, stream>>>(src, dst, E, NBK, SCN, H,
                                      W0, W1, W2, Wo, Wt1, Wt2, Wt3, Wz1, Wz2, Wz3);
  int NBs = (SCN2 + 2047) / 2048;
  scanA<<<NBs, 256, 0, stream>>>(H, SCN2, H2, blocksums);
  scanBC<<<NBs, 256, 0, stream>>>(H2, blocksums, NBs, SCN2);
  p1scatter<<<G1, 512, 0, stream>>>(src, dst, E, NBK, SCN, H2, ebuf, sbuf);
  p2build<<<2 * NBK, 256, 0, stream>>>(ebuf, sbuf, H2, E, N, NBK, SCN,
                                       offsets, csr, out_norm, in_norm);

  dim3 blk(256);
  int rb = NP / 128;
  int ab = (N + 3) / 4;

  gemm_layer<true, 0><<<rb, blk, 0, stream>>>(feats, N, Wt1, nullptr, ybuf, out_norm, nullptr);
  agg_kernel<<<ab, blk, 0, stream>>>(ybuf, (uint*)h1, csr, offsets, in_norm, b0, N);
  gemm_layer<false, 1><<<rb, blk, 0, stream>>>(h1, N, Wt2, Wz1, ybuf, out_norm, zp);
  agg_kernel<<<ab, blk, 0, stream>>>(ybuf, (uint*)h2, csr, offsets, in_norm, b1, N);
  gemm_layer<false, 2><<<rb, blk, 0, stream>>>(h2, N, Wt3, Wz2, ybuf, out_norm, zp);
  // h3 reuses h1's buffer (h1 is dead after gemm2's A-read)
  agg_kernel<<<ab, blk, 0, stream>>>(ybuf, (uint*)h1, csr, offsets, in_norm, b2, N);
  gemm_z3<<<rb, blk, 0, stream>>>(h1, zp, N, Wz3, zbb);
  pool_kernel<<<ab, blk, 0, stream>>>(zbb, out, csr, offsets, bo, N);
}